// Round 4
// baseline (2003.469 us; speedup 1.0000x reference)
//
#include <hip/hip_runtime.h>
#include <math.h>

#define BATCH     512
#define T_PAST_   360
#define T_FUT_    1800
#define IN_SZ     3
#define H_SZ      64
#define FUT_SEQ   50
#define WSPF_     34
#define MAX_STEPS (FUT_SEQ * WSPF_)      // 1700
#define T_TOT     (T_PAST_ + MAX_STEPS)  // 2060

__device__ __forceinline__ float rcp_(float x) {
    return __builtin_amdgcn_rcpf(x);     // v_rcp_f32
}

__device__ __forceinline__ float sigmoid_(float x) {
    return rcp_(1.0f + __expf(-x));
}

__device__ __forceinline__ float tanh_(float x) {
    float a = fabsf(x);
    float e = __expf(-2.0f * a);         // in (0,1], no overflow
    float t = (1.0f - e) * rcp_(1.0f + e);
    return copysignf(t, x);
}

// wave-uniform broadcast of lane `src`'s value via v_readlane -> SGPR operand
__device__ __forceinline__ float bcast_(float v, int src) {
    return __int_as_float(__builtin_amdgcn_readlane(__float_as_int(v), src));
}

// One wave (64 threads) per batch element. Lane l owns hidden unit l and the
// four W_hh rows {l, 64+l, 128+l, 192+l} in VGPRs. The entire recurrence runs
// in registers: h broadcast by readlane, gate activations + c/h update in-lane.
// No __syncthreads and no LDS access to recurrent state inside the time loop.
__global__ __launch_bounds__(64, 1)
void lstm_fused_kernel(const float* __restrict__ wave_input,   // [B, 360, 3]
                       const float* __restrict__ wave_future,  // [B, 1800, 3]
                       const float* __restrict__ W_ih,         // [256, 3]
                       const float* __restrict__ W_hh,         // [256, 64]
                       const float* __restrict__ b_ih,         // [256]
                       const float* __restrict__ b_hh,         // [256]
                       const float* __restrict__ W_proj,       // [64, 64]
                       const float* __restrict__ b_proj,       // [64]
                       float* __restrict__ out)                // [B, 50, 64]
{
    __shared__ __align__(16) float x_lds[T_TOT * IN_SZ];   // 24.7 KB
    __shared__ __align__(16) float wproj_lds[H_SZ * 65];   // 16.6 KB, padded

    const int b    = blockIdx.x;
    const int lane = threadIdx.x;      // 0..63 == hidden unit index

    // ---- stage x sequence into LDS (coalesced, one-time) ----
    {
        const float* wi = wave_input + (size_t)b * (T_PAST_ * IN_SZ);
        for (int i = lane; i < T_PAST_ * IN_SZ; i += 64) x_lds[i] = wi[i];
        const float* wf = wave_future + (size_t)b * (T_FUT_ * IN_SZ);
        for (int i = lane; i < MAX_STEPS * IN_SZ; i += 64)
            x_lds[T_PAST_ * IN_SZ + i] = wf[i];
    }
    // ---- W_proj rows into LDS, stride 65: lane l reads row l -> banks (l+m)%32,
    //      exactly 2 lanes/bank = conflict-free on CDNA ----
    for (int i = lane; i < H_SZ * H_SZ; i += 64) {
        int r = i >> 6, cc = i & 63;
        wproj_lds[r * 65 + cc] = W_proj[i];
    }

    // ---- recurrent weights: 4 gate rows of W_hh in 256 VGPRs ----
    float wi_[H_SZ], wf_[H_SZ], wg_[H_SZ], wo_[H_SZ];
    {
        const float4* pi = (const float4*)(W_hh + (size_t)(0 * H_SZ + lane) * H_SZ);
        const float4* pf = (const float4*)(W_hh + (size_t)(1 * H_SZ + lane) * H_SZ);
        const float4* pg = (const float4*)(W_hh + (size_t)(2 * H_SZ + lane) * H_SZ);
        const float4* po = (const float4*)(W_hh + (size_t)(3 * H_SZ + lane) * H_SZ);
        #pragma unroll
        for (int q = 0; q < 16; ++q) {
            float4 v;
            v = pi[q]; wi_[4*q]=v.x; wi_[4*q+1]=v.y; wi_[4*q+2]=v.z; wi_[4*q+3]=v.w;
            v = pf[q]; wf_[4*q]=v.x; wf_[4*q+1]=v.y; wf_[4*q+2]=v.z; wf_[4*q+3]=v.w;
            v = pg[q]; wg_[4*q]=v.x; wg_[4*q+1]=v.y; wg_[4*q+2]=v.z; wg_[4*q+3]=v.w;
            v = po[q]; wo_[4*q]=v.x; wo_[4*q+1]=v.y; wo_[4*q+2]=v.z; wo_[4*q+3]=v.w;
        }
    }
    // per-gate W_ih rows and combined biases
    const float wihi0 = W_ih[(0*H_SZ+lane)*3+0], wihi1 = W_ih[(0*H_SZ+lane)*3+1], wihi2 = W_ih[(0*H_SZ+lane)*3+2];
    const float wihf0 = W_ih[(1*H_SZ+lane)*3+0], wihf1 = W_ih[(1*H_SZ+lane)*3+1], wihf2 = W_ih[(1*H_SZ+lane)*3+2];
    const float wihg0 = W_ih[(2*H_SZ+lane)*3+0], wihg1 = W_ih[(2*H_SZ+lane)*3+1], wihg2 = W_ih[(2*H_SZ+lane)*3+2];
    const float wiho0 = W_ih[(3*H_SZ+lane)*3+0], wiho1 = W_ih[(3*H_SZ+lane)*3+1], wiho2 = W_ih[(3*H_SZ+lane)*3+2];
    const float bi = b_ih[0*H_SZ+lane] + b_hh[0*H_SZ+lane];
    const float bf = b_ih[1*H_SZ+lane] + b_hh[1*H_SZ+lane];
    const float bg = b_ih[2*H_SZ+lane] + b_hh[2*H_SZ+lane];
    const float bo = b_ih[3*H_SZ+lane] + b_hh[3*H_SZ+lane];
    const float bpj = b_proj[lane];

    float h = 0.0f, c = 0.0f;          // unit `lane`'s state
    float* outb = out + (size_t)b * (FUT_SEQ * H_SZ);
    int next_cp = T_PAST_ + WSPF_ - 1;
    int cp_k = 0;

    __syncthreads();                    // staging visible (single wave)

    for (int t = 0; t < T_TOT; ++t) {
        // x_t is identical for all lanes: uniform-address LDS reads (broadcast)
        float x0 = x_lds[t * 3 + 0];
        float x1 = x_lds[t * 3 + 1];
        float x2 = x_lds[t * 3 + 2];

        float ai = fmaf(wihi0, x0, fmaf(wihi1, x1, fmaf(wihi2, x2, bi)));
        float af = fmaf(wihf0, x0, fmaf(wihf1, x1, fmaf(wihf2, x2, bf)));
        float ag = fmaf(wihg0, x0, fmaf(wihg1, x1, fmaf(wihg2, x2, bg)));
        float ao = fmaf(wiho0, x0, fmaf(wiho1, x1, fmaf(wiho2, x2, bo)));

        // ---- W_hh @ h : h[k] broadcast from lane k via readlane (SGPR) ----
        #pragma unroll
        for (int k = 0; k < H_SZ; ++k) {
            float hk = bcast_(h, k);
            ai = fmaf(wi_[k], hk, ai);
            af = fmaf(wf_[k], hk, af);
            ag = fmaf(wg_[k], hk, ag);
            ao = fmaf(wo_[k], hk, ao);
        }

        // ---- gate activations + state update, fully in-lane ----
        float gi = sigmoid_(ai);
        float gf = sigmoid_(af);
        float gg = tanh_(ag);
        float go = sigmoid_(ao);
        c = fmaf(gf, c, gi * gg);
        h = go * tanh_(c);

        if (t == next_cp) {            // wave-uniform
            // out[b, cp_k, lane] = b_proj[lane] + sum_m W_proj[lane, m] * h[m]
            float p = bpj;
            #pragma unroll 8
            for (int m = 0; m < H_SZ; ++m)
                p = fmaf(wproj_lds[lane * 65 + m], bcast_(h, m), p);
            outb[cp_k * H_SZ + lane] = p;
            next_cp += WSPF_;
            ++cp_k;
        }
    }
}

extern "C" void kernel_launch(void* const* d_in, const int* in_sizes, int n_in,
                              void* d_out, int out_size, void* d_ws, size_t ws_size,
                              hipStream_t stream) {
    const float* wave_input  = (const float*)d_in[0];
    const float* wave_future = (const float*)d_in[1];
    const float* W_ih        = (const float*)d_in[2];
    const float* W_hh        = (const float*)d_in[3];
    const float* b_ih        = (const float*)d_in[4];
    const float* b_hh        = (const float*)d_in[5];
    const float* W_proj      = (const float*)d_in[6];
    const float* b_proj      = (const float*)d_in[7];
    float* out               = (float*)d_out;

    lstm_fused_kernel<<<BATCH, 64, 0, stream>>>(
        wave_input, wave_future, W_ih, W_hh, b_ih, b_hh, W_proj, b_proj, out);
}